// Round 4
// baseline (1014.160 us; speedup 1.0000x reference)
//
#include <hip/hip_runtime.h>
#include <math.h>

#define KVOX 15000
#define TP 35
#define CIN 7
#define CM1 16
#define CM2 64
#define NPTS (KVOX * TP)
#define DD 10
#define HH 400
#define WWID 352
#define EPSBN 1e-5f
#define NB1 1024
#define NBV 3750   // KVOX / 4 voxels-per-block
#define NBZ 2048   // zero-fill blocks

typedef float vfloat4 __attribute__((ext_vector_type(4)));

// ---------------- dense-grid zero fill (the long pole) ----------------
// 721 MB of zeros via float4 nontemporal stores; exactly out_size*4 bytes.
__global__ __launch_bounds__(256) void zero_kernel(vfloat4* __restrict__ out, int n4)
{
    const vfloat4 z = {0.f, 0.f, 0.f, 0.f};
    int stride = NBZ * 256;
    for (int i = blockIdx.x * 256 + threadIdx.x; i < n4; i += stride)
        __builtin_nontemporal_store(z, &out[i]);
}

// ---------------- layer-1 BN stats ----------------
__global__ __launch_bounds__(256) void stats1_kernel(
    const float* __restrict__ feat, const float* __restrict__ W1,
    const float* __restrict__ b1, float* __restrict__ partial1)
{
    __shared__ float w1s[CIN * CM1];
    __shared__ float b1s[CM1];
    __shared__ float red[4][32];
    int tid = threadIdx.x;
    if (tid < CIN * CM1) w1s[tid] = W1[tid];
    if (tid < CM1) b1s[tid] = b1[tid];
    __syncthreads();

    float s[CM1], q[CM1];
#pragma unroll
    for (int c = 0; c < CM1; ++c) { s[c] = 0.f; q[c] = 0.f; }

    for (int i = blockIdx.x * 256 + tid; i < NPTS; i += NB1 * 256) {
        float f[CIN];
#pragma unroll
        for (int j = 0; j < CIN; ++j) f[j] = feat[(size_t)i * CIN + j];
#pragma unroll
        for (int c = 0; c < CM1; ++c) {
            float acc = b1s[c];
#pragma unroll
            for (int j = 0; j < CIN; ++j) acc = fmaf(f[j], w1s[j * CM1 + c], acc);
            float pw = fmaxf(acc, 0.f);
            s[c] += pw; q[c] += pw * pw;
        }
    }
#pragma unroll
    for (int c = 0; c < CM1; ++c) {
#pragma unroll
        for (int off = 32; off > 0; off >>= 1) {
            s[c] += __shfl_xor(s[c], off);
            q[c] += __shfl_xor(q[c], off);
        }
    }
    int wid = tid >> 6, lane = tid & 63;
    if (lane == 0) {
#pragma unroll
        for (int c = 0; c < CM1; ++c) { red[wid][c] = s[c]; red[wid][CM1 + c] = q[c]; }
    }
    __syncthreads();
    if (tid < 32)
        partial1[blockIdx.x * 32 + tid] =
            red[0][tid] + red[1][tid] + red[2][tid] + red[3][tid];
}

__global__ __launch_bounds__(256) void reduce1_kernel(
    const float* __restrict__ partial1, const float* __restrict__ g1,
    const float* __restrict__ be1, float* __restrict__ coef1)
{
    __shared__ float acc[8][32];
    __shared__ float tot[32];
    int tid = threadIdx.x;
    int c = tid & 31, part = tid >> 5;
    float v = 0.f;
    for (int b = part; b < NB1; b += 8) v += partial1[b * 32 + c];
    acc[part][c] = v;
    __syncthreads();
    if (tid < 32) {
        float t = 0.f;
#pragma unroll
        for (int p = 0; p < 8; ++p) t += acc[p][tid];
        tot[tid] = t;
    }
    __syncthreads();
    if (tid < CM1) {
        float inv = 1.f / (float)NPTS;
        float mu = tot[tid] * inv;
        float var = tot[CM1 + tid] * inv - mu * mu;
        float a = g1[tid] * rsqrtf(var + EPSBN);
        coef1[tid] = a;                       // scale
        coef1[CM1 + tid] = be1[tid] - mu * a; // shift
    }
}

// ---------------- wave-per-voxel VFE: recompute L1, run L2 ----------------
// FINAL=false: accumulate layer-2 BN stats. FINAL=true: bn2, maxes, scatter.
template <bool FINAL>
__global__ __launch_bounds__(256) void vfe_kernel(
    const float* __restrict__ feat,
    const float* __restrict__ W1g, const float* __restrict__ b1g,
    const float* __restrict__ coef1,
    const float* __restrict__ W2g, const float* __restrict__ b2g,
    const float* __restrict__ coef2,
    const int*  __restrict__ coord,
    float* __restrict__ partial2,
    float* __restrict__ out)
{
    __shared__ float sfeat[4][TP * CIN + 11];      // 245 -> 256 per wave
    alignas(16) __shared__ float scat[4][TP * 32]; // 1120 per wave, 16B-aligned rows
    __shared__ float smask[4][TP + 5];
    __shared__ float red2[4][2 * CM2];

    int tid = threadIdx.x, wid = tid >> 6, lane = tid & 63;
    int k = blockIdx.x * 4 + wid;                  // exact: NBV*4 == KVOX
    int tg = lane >> 4, c1 = lane & 15;

    // per-lane constants
    float w1r[CIN];
#pragma unroll
    for (int j = 0; j < CIN; ++j) w1r[j] = W1g[j * CM1 + c1];
    float b1r = b1g[c1];
    float a1r = coef1[c1], d1r = coef1[CM1 + c1];
    float w2r[32];
#pragma unroll
    for (int j = 0; j < 32; ++j) w2r[j] = W2g[j * CM2 + lane];
    float b2r = b2g[lane];
    float a2r = 0.f, d2r = 0.f;
    if constexpr (FINAL) { a2r = coef2[lane]; d2r = coef2[CM2 + lane]; }

    float* F = sfeat[wid];
    float* CT = scat[wid];
    float* M = smask[wid];

    // stage this voxel's 35x7 feature tile
    for (int i = lane; i < TP * CIN; i += 64)
        F[i] = feat[(size_t)k * (TP * CIN) + i];
    __syncthreads();

    // ---- phase 1: pw1 -> bn1, unmasked max over T, masked cat ----
    float maxv = -INFINITY;
#pragma unroll
    for (int it = 0; it < 9; ++it) {
        int t = tg + 4 * it;                       // covers t=0..34 exactly once
        if (t < TP) {
            float fv0 = F[t * CIN];
            float m7 = fv0;
            float acc = fmaf(fv0, w1r[0], b1r);
#pragma unroll
            for (int j = 1; j < CIN; ++j) {
                float fv = F[t * CIN + j];
                m7 = fmaxf(m7, fv);
                acc = fmaf(fv, w1r[j], acc);
            }
            float maskv = (m7 != 0.f) ? 1.f : 0.f;
            float pw = fmaxf(acc, 0.f);
            float bn = fmaf(pw, a1r, d1r);
            maxv = fmaxf(maxv, bn);                // agg1 uses UNMASKED bn
            CT[t * 32 + c1] = bn * maskv;
            if (c1 == 0) M[t] = maskv;
        }
    }
    maxv = fmaxf(maxv, __shfl_xor(maxv, 16));
    maxv = fmaxf(maxv, __shfl_xor(maxv, 32));      // agg1[c1] in all lanes
#pragma unroll
    for (int it = 0; it < 9; ++it) {
        int t = tg + 4 * it;
        if (t < TP) CT[t * 32 + 16 + c1] = maxv * M[t];
    }
    // all LDS deps above are within-wave (in-order LDS) — no block barrier needed

    // ---- phase 2: lane = output channel of the 32->64 linear ----
    float s_acc = 0.f, q_acc = 0.f;
    float agg2 = -INFINITY, v1 = -INFINITY, mmin = 1.f;
    for (int t = 0; t < TP; ++t) {
        const float4* r4 = reinterpret_cast<const float4*>(&CT[t * 32]);
        float acc0 = b2r, acc1 = 0.f;
#pragma unroll
        for (int i = 0; i < 8; i += 2) {
            float4 va = r4[i], vb = r4[i + 1];
            acc0 = fmaf(va.x, w2r[4 * i + 0], acc0);
            acc0 = fmaf(va.y, w2r[4 * i + 1], acc0);
            acc0 = fmaf(va.z, w2r[4 * i + 2], acc0);
            acc0 = fmaf(va.w, w2r[4 * i + 3], acc0);
            acc1 = fmaf(vb.x, w2r[4 * i + 4], acc1);
            acc1 = fmaf(vb.y, w2r[4 * i + 5], acc1);
            acc1 = fmaf(vb.z, w2r[4 * i + 6], acc1);
            acc1 = fmaf(vb.w, w2r[4 * i + 7], acc1);
        }
        float pw = fmaxf(acc0 + acc1, 0.f);
        if constexpr (!FINAL) {
            s_acc += pw; q_acc += pw * pw;
        } else {
            float bn = fmaf(pw, a2r, d2r);
            agg2 = fmaxf(agg2, bn);                // agg2 over UNMASKED bn2
            float mk = M[t];
            v1 = fmaxf(v1, bn * mk);               // voxelwise max of masked cat
            mmin = fminf(mmin, mk);
        }
    }

    if constexpr (!FINAL) {
        red2[wid][lane] = s_acc;
        red2[wid][CM2 + lane] = q_acc;
        __syncthreads();
        if (tid < 2 * CM2)
            partial2[(size_t)blockIdx.x * (2 * CM2) + tid] =
                red2[0][tid] + red2[1][tid] + red2[2][tid] + red2[3][tid];
    } else {
        float v2 = (mmin == 0.f) ? fmaxf(agg2, 0.f) : agg2; // masked max of agg2
        int cd = coord[k * 4 + 1], ch = coord[k * 4 + 2], cw = coord[k * 4 + 3];
        size_t base = ((((size_t)cd * HH) + ch) * WWID + cw) * 128;
        atomicAdd(&out[base + lane], v1);
        atomicAdd(&out[base + 64 + lane], v2);
    }
}

__global__ __launch_bounds__(1024) void reduce2_kernel(
    const float* __restrict__ partial2, const float* __restrict__ g2,
    const float* __restrict__ be2, float* __restrict__ coef2)
{
    __shared__ float acc[8][128];
    __shared__ float tot[128];
    int tid = threadIdx.x;
    int c = tid & 127, part = tid >> 7;
    float v = 0.f;
    for (int b = part; b < NBV; b += 8) v += partial2[(size_t)b * 128 + c];
    acc[part][c] = v;
    __syncthreads();
    if (tid < 128) {
        float t = 0.f;
#pragma unroll
        for (int p = 0; p < 8; ++p) t += acc[p][tid];
        tot[tid] = t;
    }
    __syncthreads();
    if (tid < CM2) {
        float inv = 1.f / (float)NPTS;
        float mu = tot[tid] * inv;
        float var = tot[CM2 + tid] * inv - mu * mu;
        float a = g2[tid] * rsqrtf(var + EPSBN);
        coef2[tid] = a;
        coef2[CM2 + tid] = be2[tid] - mu * a;
    }
}

extern "C" void kernel_launch(void* const* d_in, const int* in_sizes, int n_in,
                              void* d_out, int out_size, void* d_ws, size_t ws_size,
                              hipStream_t stream)
{
    const float* feat = (const float*)d_in[0];
    const int*   coord = (const int*)d_in[1];
    // d_in[2] = bs (==1, unused)
    const float* W1  = (const float*)d_in[3];
    const float* b1  = (const float*)d_in[4];
    const float* g1  = (const float*)d_in[5];
    const float* be1 = (const float*)d_in[6];
    const float* W2  = (const float*)d_in[7];
    const float* b2  = (const float*)d_in[8];
    const float* g2  = (const float*)d_in[9];
    const float* be2 = (const float*)d_in[10];
    float* out = (float*)d_out;

    float* wsf = (float*)d_ws;
    float* partial1 = wsf;                    // 1024*32   = 32768 floats
    float* partial2 = wsf + 32768;            // 3750*128  = 480000 floats
    float* coef1 = wsf + 32768 + 480000;      // 32 floats
    float* coef2 = coef1 + 32;                // 128 floats
    // total ws use: ~2.06 MB

    // the long pole: zero the 721 MB dense output grid.
    // rocclr fillBufferAligned measured 455 us / 2.88 GB WRITE_SIZE (4x
    // amplification, 10% occupancy) — hand-rolled float4 NT stores instead.
    zero_kernel<<<NBZ, 256, 0, stream>>>((vfloat4*)d_out, out_size / 4);

    stats1_kernel<<<NB1, 256, 0, stream>>>(feat, W1, b1, partial1);
    reduce1_kernel<<<1, 256, 0, stream>>>(partial1, g1, be1, coef1);
    vfe_kernel<false><<<NBV, 256, 0, stream>>>(feat, W1, b1, coef1, W2, b2,
                                               nullptr, nullptr, partial2, nullptr);
    reduce2_kernel<<<1, 1024, 0, stream>>>(partial2, g2, be2, coef2);
    vfe_kernel<true><<<NBV, 256, 0, stream>>>(feat, W1, b1, coef1, W2, b2,
                                              coef2, coord, nullptr, out);
}

// Round 5
// 1009.935 us; speedup vs baseline: 1.0042x; 1.0042x over previous
//
#include <hip/hip_runtime.h>
#include <math.h>

#define KVOX 15000
#define TP 35
#define CIN 7
#define CM1 16
#define CM2 64
#define NPTS (KVOX * TP)
#define DD 10
#define HH 400
#define WWID 352
#define EPSBN 1e-5f
#define NB1 1024
#define NBV 3750   // KVOX / 4 voxels-per-block
#define NBZ 2048   // zero-fill blocks

typedef float vfloat4 __attribute__((ext_vector_type(4)));

// ---------------- dense-grid zero fill (the long pole) ----------------
// 721 MB of zeros. PLAIN float4 stores through L2 (m13 pattern, 6.29 TB/s).
// Round-4 lesson: __builtin_nontemporal_store ran at ~1.4 TB/s on gfx950 —
// NT bypasses L2 write-combining; do NOT use it for streaming fills.
__global__ __launch_bounds__(256) void zero_kernel(vfloat4* __restrict__ out, int n4)
{
    const vfloat4 z = {0.f, 0.f, 0.f, 0.f};
    int stride = NBZ * 256;
    for (int i = blockIdx.x * 256 + threadIdx.x; i < n4; i += stride)
        out[i] = z;
}

// ---------------- layer-1 BN stats ----------------
__global__ __launch_bounds__(256) void stats1_kernel(
    const float* __restrict__ feat, const float* __restrict__ W1,
    const float* __restrict__ b1, float* __restrict__ partial1)
{
    __shared__ float w1s[CIN * CM1];
    __shared__ float b1s[CM1];
    __shared__ float red[4][32];
    int tid = threadIdx.x;
    if (tid < CIN * CM1) w1s[tid] = W1[tid];
    if (tid < CM1) b1s[tid] = b1[tid];
    __syncthreads();

    float s[CM1], q[CM1];
#pragma unroll
    for (int c = 0; c < CM1; ++c) { s[c] = 0.f; q[c] = 0.f; }

    for (int i = blockIdx.x * 256 + tid; i < NPTS; i += NB1 * 256) {
        float f[CIN];
#pragma unroll
        for (int j = 0; j < CIN; ++j) f[j] = feat[(size_t)i * CIN + j];
#pragma unroll
        for (int c = 0; c < CM1; ++c) {
            float acc = b1s[c];
#pragma unroll
            for (int j = 0; j < CIN; ++j) acc = fmaf(f[j], w1s[j * CM1 + c], acc);
            float pw = fmaxf(acc, 0.f);
            s[c] += pw; q[c] += pw * pw;
        }
    }
#pragma unroll
    for (int c = 0; c < CM1; ++c) {
#pragma unroll
        for (int off = 32; off > 0; off >>= 1) {
            s[c] += __shfl_xor(s[c], off);
            q[c] += __shfl_xor(q[c], off);
        }
    }
    int wid = tid >> 6, lane = tid & 63;
    if (lane == 0) {
#pragma unroll
        for (int c = 0; c < CM1; ++c) { red[wid][c] = s[c]; red[wid][CM1 + c] = q[c]; }
    }
    __syncthreads();
    if (tid < 32)
        partial1[blockIdx.x * 32 + tid] =
            red[0][tid] + red[1][tid] + red[2][tid] + red[3][tid];
}

__global__ __launch_bounds__(256) void reduce1_kernel(
    const float* __restrict__ partial1, const float* __restrict__ g1,
    const float* __restrict__ be1, float* __restrict__ coef1)
{
    __shared__ float acc[8][32];
    __shared__ float tot[32];
    int tid = threadIdx.x;
    int c = tid & 31, part = tid >> 5;
    float v = 0.f;
    for (int b = part; b < NB1; b += 8) v += partial1[b * 32 + c];
    acc[part][c] = v;
    __syncthreads();
    if (tid < 32) {
        float t = 0.f;
#pragma unroll
        for (int p = 0; p < 8; ++p) t += acc[p][tid];
        tot[tid] = t;
    }
    __syncthreads();
    if (tid < CM1) {
        float inv = 1.f / (float)NPTS;
        float mu = tot[tid] * inv;
        float var = tot[CM1 + tid] * inv - mu * mu;
        float a = g1[tid] * rsqrtf(var + EPSBN);
        coef1[tid] = a;                       // scale
        coef1[CM1 + tid] = be1[tid] - mu * a; // shift
    }
}

// ---------------- wave-per-voxel VFE: recompute L1, run L2 ----------------
// FINAL=false: accumulate layer-2 BN stats. FINAL=true: bn2, maxes, scatter.
template <bool FINAL>
__global__ __launch_bounds__(256) void vfe_kernel(
    const float* __restrict__ feat,
    const float* __restrict__ W1g, const float* __restrict__ b1g,
    const float* __restrict__ coef1,
    const float* __restrict__ W2g, const float* __restrict__ b2g,
    const float* __restrict__ coef2,
    const int*  __restrict__ coord,
    float* __restrict__ partial2,
    float* __restrict__ out)
{
    __shared__ float sfeat[4][TP * CIN + 11];      // 245 -> 256 per wave
    alignas(16) __shared__ float scat[4][TP * 32]; // 1120 per wave, 16B-aligned rows
    __shared__ float smask[4][TP + 5];
    __shared__ float red2[4][2 * CM2];

    int tid = threadIdx.x, wid = tid >> 6, lane = tid & 63;
    int k = blockIdx.x * 4 + wid;                  // exact: NBV*4 == KVOX
    int tg = lane >> 4, c1 = lane & 15;

    // per-lane constants
    float w1r[CIN];
#pragma unroll
    for (int j = 0; j < CIN; ++j) w1r[j] = W1g[j * CM1 + c1];
    float b1r = b1g[c1];
    float a1r = coef1[c1], d1r = coef1[CM1 + c1];
    float w2r[32];
#pragma unroll
    for (int j = 0; j < 32; ++j) w2r[j] = W2g[j * CM2 + lane];
    float b2r = b2g[lane];
    float a2r = 0.f, d2r = 0.f;
    if constexpr (FINAL) { a2r = coef2[lane]; d2r = coef2[CM2 + lane]; }

    float* F = sfeat[wid];
    float* CT = scat[wid];
    float* M = smask[wid];

    // stage this voxel's 35x7 feature tile
    for (int i = lane; i < TP * CIN; i += 64)
        F[i] = feat[(size_t)k * (TP * CIN) + i];
    __syncthreads();

    // ---- phase 1: pw1 -> bn1, unmasked max over T, masked cat ----
    float maxv = -INFINITY;
#pragma unroll
    for (int it = 0; it < 9; ++it) {
        int t = tg + 4 * it;                       // covers t=0..34 exactly once
        if (t < TP) {
            float fv0 = F[t * CIN];
            float m7 = fv0;
            float acc = fmaf(fv0, w1r[0], b1r);
#pragma unroll
            for (int j = 1; j < CIN; ++j) {
                float fv = F[t * CIN + j];
                m7 = fmaxf(m7, fv);
                acc = fmaf(fv, w1r[j], acc);
            }
            float maskv = (m7 != 0.f) ? 1.f : 0.f;
            float pw = fmaxf(acc, 0.f);
            float bn = fmaf(pw, a1r, d1r);
            maxv = fmaxf(maxv, bn);                // agg1 uses UNMASKED bn
            CT[t * 32 + c1] = bn * maskv;
            if (c1 == 0) M[t] = maskv;
        }
    }
    maxv = fmaxf(maxv, __shfl_xor(maxv, 16));
    maxv = fmaxf(maxv, __shfl_xor(maxv, 32));      // agg1[c1] in all lanes
#pragma unroll
    for (int it = 0; it < 9; ++it) {
        int t = tg + 4 * it;
        if (t < TP) CT[t * 32 + 16 + c1] = maxv * M[t];
    }
    // all LDS deps above are within-wave (in-order LDS) — no block barrier needed

    // ---- phase 2: lane = output channel of the 32->64 linear ----
    float s_acc = 0.f, q_acc = 0.f;
    float agg2 = -INFINITY, v1 = -INFINITY, mmin = 1.f;
    for (int t = 0; t < TP; ++t) {
        const float4* r4 = reinterpret_cast<const float4*>(&CT[t * 32]);
        float acc0 = b2r, acc1 = 0.f;
#pragma unroll
        for (int i = 0; i < 8; i += 2) {
            float4 va = r4[i], vb = r4[i + 1];
            acc0 = fmaf(va.x, w2r[4 * i + 0], acc0);
            acc0 = fmaf(va.y, w2r[4 * i + 1], acc0);
            acc0 = fmaf(va.z, w2r[4 * i + 2], acc0);
            acc0 = fmaf(va.w, w2r[4 * i + 3], acc0);
            acc1 = fmaf(vb.x, w2r[4 * i + 4], acc1);
            acc1 = fmaf(vb.y, w2r[4 * i + 5], acc1);
            acc1 = fmaf(vb.z, w2r[4 * i + 6], acc1);
            acc1 = fmaf(vb.w, w2r[4 * i + 7], acc1);
        }
        float pw = fmaxf(acc0 + acc1, 0.f);
        if constexpr (!FINAL) {
            s_acc += pw; q_acc += pw * pw;
        } else {
            float bn = fmaf(pw, a2r, d2r);
            agg2 = fmaxf(agg2, bn);                // agg2 over UNMASKED bn2
            float mk = M[t];
            v1 = fmaxf(v1, bn * mk);               // voxelwise max of masked cat
            mmin = fminf(mmin, mk);
        }
    }

    if constexpr (!FINAL) {
        red2[wid][lane] = s_acc;
        red2[wid][CM2 + lane] = q_acc;
        __syncthreads();
        if (tid < 2 * CM2)
            partial2[(size_t)blockIdx.x * (2 * CM2) + tid] =
                red2[0][tid] + red2[1][tid] + red2[2][tid] + red2[3][tid];
    } else {
        float v2 = (mmin == 0.f) ? fmaxf(agg2, 0.f) : agg2; // masked max of agg2
        int cd = coord[k * 4 + 1], ch = coord[k * 4 + 2], cw = coord[k * 4 + 3];
        size_t base = ((((size_t)cd * HH) + ch) * WWID + cw) * 128;
        atomicAdd(&out[base + lane], v1);
        atomicAdd(&out[base + 64 + lane], v2);
    }
}

__global__ __launch_bounds__(1024) void reduce2_kernel(
    const float* __restrict__ partial2, const float* __restrict__ g2,
    const float* __restrict__ be2, float* __restrict__ coef2)
{
    __shared__ float acc[8][128];
    __shared__ float tot[128];
    int tid = threadIdx.x;
    int c = tid & 127, part = tid >> 7;
    float v = 0.f;
    for (int b = part; b < NBV; b += 8) v += partial2[(size_t)b * 128 + c];
    acc[part][c] = v;
    __syncthreads();
    if (tid < 128) {
        float t = 0.f;
#pragma unroll
        for (int p = 0; p < 8; ++p) t += acc[p][tid];
        tot[tid] = t;
    }
    __syncthreads();
    if (tid < CM2) {
        float inv = 1.f / (float)NPTS;
        float mu = tot[tid] * inv;
        float var = tot[CM2 + tid] * inv - mu * mu;
        float a = g2[tid] * rsqrtf(var + EPSBN);
        coef2[tid] = a;
        coef2[CM2 + tid] = be2[tid] - mu * a;
    }
}

extern "C" void kernel_launch(void* const* d_in, const int* in_sizes, int n_in,
                              void* d_out, int out_size, void* d_ws, size_t ws_size,
                              hipStream_t stream)
{
    const float* feat = (const float*)d_in[0];
    const int*   coord = (const int*)d_in[1];
    // d_in[2] = bs (==1, unused)
    const float* W1  = (const float*)d_in[3];
    const float* b1  = (const float*)d_in[4];
    const float* g1  = (const float*)d_in[5];
    const float* be1 = (const float*)d_in[6];
    const float* W2  = (const float*)d_in[7];
    const float* b2  = (const float*)d_in[8];
    const float* g2  = (const float*)d_in[9];
    const float* be2 = (const float*)d_in[10];
    float* out = (float*)d_out;

    float* wsf = (float*)d_ws;
    float* partial1 = wsf;                    // 1024*32   = 32768 floats
    float* partial2 = wsf + 32768;            // 3750*128  = 480000 floats
    float* coef1 = wsf + 32768 + 480000;      // 32 floats
    float* coef2 = coef1 + 32;                // 128 floats
    // total ws use: ~2.06 MB

    // the long pole: zero the 721 MB dense output grid with plain float4
    // stores (NT stores measured ~1.4 TB/s; rocclr fill 4x-amplified).
    zero_kernel<<<NBZ, 256, 0, stream>>>((vfloat4*)d_out, out_size / 4);

    stats1_kernel<<<NB1, 256, 0, stream>>>(feat, W1, b1, partial1);
    reduce1_kernel<<<1, 256, 0, stream>>>(partial1, g1, be1, coef1);
    vfe_kernel<false><<<NBV, 256, 0, stream>>>(feat, W1, b1, coef1, W2, b2,
                                               nullptr, nullptr, partial2, nullptr);
    reduce2_kernel<<<1, 1024, 0, stream>>>(partial2, g2, be2, coef2);
    vfe_kernel<true><<<NBV, 256, 0, stream>>>(feat, W1, b1, coef1, W2, b2,
                                              coef2, coord, nullptr, out);
}

// Round 7
// 935.730 us; speedup vs baseline: 1.0838x; 1.0793x over previous
//
#include <hip/hip_runtime.h>
#include <math.h>

#define KVOX 15000
#define TP 35
#define CIN 7
#define CM1 16
#define CM2 64
#define NPTS (KVOX * TP)
#define DD 10
#define HH 400
#define WWID 352
#define NCELL (DD * HH * WWID)   // 1,408,000
#define EPSBN 1e-5f
#define NB1 256
#define NBV 3750   // KVOX / 4 voxels-per-block

typedef float vfloat4 __attribute__((ext_vector_type(4)));
typedef int   vint4   __attribute__((ext_vector_type(4)));

// ---------------- init: table = INT_MAX, compact = 0 ----------------
// table: NCELL ints (5.6 MB); compact: KVOX*128 floats (7.7 MB). 16B stores.
#define NT4 (NCELL / 4)              // 352,000 int4
#define NC4 (KVOX * 128 / 4)         // 480,000 float4
#define NBI ((NT4 + NC4 + 255) / 256)
__global__ __launch_bounds__(256) void init_kernel(vint4* __restrict__ table4,
                                                   vfloat4* __restrict__ comp4)
{
    int i = blockIdx.x * 256 + threadIdx.x;
    if (i < NT4) {
        table4[i] = (vint4){0x7FFFFFFF, 0x7FFFFFFF, 0x7FFFFFFF, 0x7FFFFFFF};
    } else if (i - NT4 < NC4) {
        comp4[i - NT4] = (vfloat4){0.f, 0.f, 0.f, 0.f};
    }
}

// ---------------- layer-1 BN stats + winner-table build ----------------
__global__ __launch_bounds__(256) void stats1_kernel(
    const float* __restrict__ feat, const int* __restrict__ coord,
    const float* __restrict__ W1, const float* __restrict__ b1,
    float* __restrict__ partial1, int* __restrict__ table)
{
    __shared__ float w1s[CIN * CM1];
    __shared__ float b1s[CM1];
    __shared__ float red[4][32];
    int tid = threadIdx.x;
    if (tid < CIN * CM1) w1s[tid] = W1[tid];
    if (tid < CM1) b1s[tid] = b1[tid];

    // build cell -> winner(min voxel id) table; duplicates share the winner
    int g = blockIdx.x * 256 + tid;
    if (g < KVOX) {
        int cell = (coord[g * 4 + 1] * HH + coord[g * 4 + 2]) * WWID + coord[g * 4 + 3];
        atomicMin(&table[cell], g);
    }
    __syncthreads();

    float s[CM1], q[CM1];
#pragma unroll
    for (int c = 0; c < CM1; ++c) { s[c] = 0.f; q[c] = 0.f; }

    for (int i = blockIdx.x * 256 + tid; i < NPTS; i += NB1 * 256) {
        float f[CIN];
#pragma unroll
        for (int j = 0; j < CIN; ++j) f[j] = feat[(size_t)i * CIN + j];
#pragma unroll
        for (int c = 0; c < CM1; ++c) {
            float acc = b1s[c];
#pragma unroll
            for (int j = 0; j < CIN; ++j) acc = fmaf(f[j], w1s[j * CM1 + c], acc);
            float pw = fmaxf(acc, 0.f);
            s[c] += pw; q[c] += pw * pw;
        }
    }
#pragma unroll
    for (int c = 0; c < CM1; ++c) {
#pragma unroll
        for (int off = 32; off > 0; off >>= 1) {
            s[c] += __shfl_xor(s[c], off);
            q[c] += __shfl_xor(q[c], off);
        }
    }
    int wid = tid >> 6, lane = tid & 63;
    if (lane == 0) {
#pragma unroll
        for (int c = 0; c < CM1; ++c) { red[wid][c] = s[c]; red[wid][CM1 + c] = q[c]; }
    }
    __syncthreads();
    if (tid < 32)
        partial1[blockIdx.x * 32 + tid] =
            red[0][tid] + red[1][tid] + red[2][tid] + red[3][tid];
}

__global__ __launch_bounds__(256) void reduce1_kernel(
    const float* __restrict__ partial1, const float* __restrict__ g1,
    const float* __restrict__ be1, float* __restrict__ coef1)
{
    __shared__ float acc[8][32];
    __shared__ float tot[32];
    int tid = threadIdx.x;
    int c = tid & 31, part = tid >> 5;
    float v = 0.f;
    for (int b = part; b < NB1; b += 8) v += partial1[b * 32 + c];
    acc[part][c] = v;
    __syncthreads();
    if (tid < 32) {
        float t = 0.f;
#pragma unroll
        for (int p = 0; p < 8; ++p) t += acc[p][tid];
        tot[tid] = t;
    }
    __syncthreads();
    if (tid < CM1) {
        float inv = 1.f / (float)NPTS;
        float mu = tot[tid] * inv;
        float var = tot[CM1 + tid] * inv - mu * mu;
        float a = g1[tid] * rsqrtf(var + EPSBN);
        coef1[tid] = a;                       // scale
        coef1[CM1 + tid] = be1[tid] - mu * a; // shift
    }
}

// ---------------- wave-per-voxel VFE: recompute L1, run L2 ----------------
// FINAL=false: accumulate layer-2 BN stats. FINAL=true: bn2, maxes,
// accumulate into compact[winner] (L2-resident) instead of dense HBM atomics.
template <bool FINAL>
__global__ __launch_bounds__(256) void vfe_kernel(
    const float* __restrict__ feat,
    const float* __restrict__ W1g, const float* __restrict__ b1g,
    const float* __restrict__ coef1,
    const float* __restrict__ W2g, const float* __restrict__ b2g,
    const float* __restrict__ coef2,
    const int*  __restrict__ coord,
    const int*  __restrict__ table,
    float* __restrict__ partial2,
    float* __restrict__ compact)
{
    __shared__ float sfeat[4][TP * CIN + 11];      // 245 -> 256 per wave
    alignas(16) __shared__ float scat[4][TP * 32]; // 1120 per wave, 16B-aligned rows
    __shared__ float smask[4][TP + 5];
    __shared__ float red2[4][2 * CM2];

    int tid = threadIdx.x, wid = tid >> 6, lane = tid & 63;
    int k = blockIdx.x * 4 + wid;                  // exact: NBV*4 == KVOX
    int tg = lane >> 4, c1 = lane & 15;

    // per-lane constants
    float w1r[CIN];
#pragma unroll
    for (int j = 0; j < CIN; ++j) w1r[j] = W1g[j * CM1 + c1];
    float b1r = b1g[c1];
    float a1r = coef1[c1], d1r = coef1[CM1 + c1];
    float w2r[32];
#pragma unroll
    for (int j = 0; j < 32; ++j) w2r[j] = W2g[j * CM2 + lane];
    float b2r = b2g[lane];
    float a2r = 0.f, d2r = 0.f;
    if constexpr (FINAL) { a2r = coef2[lane]; d2r = coef2[CM2 + lane]; }

    float* F = sfeat[wid];
    float* CT = scat[wid];
    float* M = smask[wid];

    // stage this voxel's 35x7 feature tile
    for (int i = lane; i < TP * CIN; i += 64)
        F[i] = feat[(size_t)k * (TP * CIN) + i];
    __syncthreads();

    // ---- phase 1: pw1 -> bn1, unmasked max over T, masked cat ----
    float maxv = -INFINITY;
#pragma unroll
    for (int it = 0; it < 9; ++it) {
        int t = tg + 4 * it;                       // covers t=0..34 exactly once
        if (t < TP) {
            float fv0 = F[t * CIN];
            float m7 = fv0;
            float acc = fmaf(fv0, w1r[0], b1r);
#pragma unroll
            for (int j = 1; j < CIN; ++j) {
                float fv = F[t * CIN + j];
                m7 = fmaxf(m7, fv);
                acc = fmaf(fv, w1r[j], acc);
            }
            float maskv = (m7 != 0.f) ? 1.f : 0.f;
            float pw = fmaxf(acc, 0.f);
            float bn = fmaf(pw, a1r, d1r);
            maxv = fmaxf(maxv, bn);                // agg1 uses UNMASKED bn
            CT[t * 32 + c1] = bn * maskv;
            if (c1 == 0) M[t] = maskv;
        }
    }
    maxv = fmaxf(maxv, __shfl_xor(maxv, 16));
    maxv = fmaxf(maxv, __shfl_xor(maxv, 32));      // agg1[c1] in all lanes
#pragma unroll
    for (int it = 0; it < 9; ++it) {
        int t = tg + 4 * it;
        if (t < TP) CT[t * 32 + 16 + c1] = maxv * M[t];
    }
    // all LDS deps above are within-wave (in-order LDS) — no block barrier needed

    // ---- phase 2: lane = output channel of the 32->64 linear ----
    float s_acc = 0.f, q_acc = 0.f;
    float agg2 = -INFINITY, v1 = -INFINITY, mmin = 1.f;
    for (int t = 0; t < TP; ++t) {
        const float4* r4 = reinterpret_cast<const float4*>(&CT[t * 32]);
        float acc0 = b2r, acc1 = 0.f;
#pragma unroll
        for (int i = 0; i < 8; i += 2) {
            float4 va = r4[i], vb = r4[i + 1];
            acc0 = fmaf(va.x, w2r[4 * i + 0], acc0);
            acc0 = fmaf(va.y, w2r[4 * i + 1], acc0);
            acc0 = fmaf(va.z, w2r[4 * i + 2], acc0);
            acc0 = fmaf(va.w, w2r[4 * i + 3], acc0);
            acc1 = fmaf(vb.x, w2r[4 * i + 4], acc1);
            acc1 = fmaf(vb.y, w2r[4 * i + 5], acc1);
            acc1 = fmaf(vb.z, w2r[4 * i + 6], acc1);
            acc1 = fmaf(vb.w, w2r[4 * i + 7], acc1);
        }
        float pw = fmaxf(acc0 + acc1, 0.f);
        if constexpr (!FINAL) {
            s_acc += pw; q_acc += pw * pw;
        } else {
            float bn = fmaf(pw, a2r, d2r);
            agg2 = fmaxf(agg2, bn);                // agg2 over UNMASKED bn2
            float mk = M[t];
            v1 = fmaxf(v1, bn * mk);               // voxelwise max of masked cat
            mmin = fminf(mmin, mk);
        }
    }

    if constexpr (!FINAL) {
        red2[wid][lane] = s_acc;
        red2[wid][CM2 + lane] = q_acc;
        __syncthreads();
        if (tid < 2 * CM2)
            partial2[(size_t)blockIdx.x * (2 * CM2) + tid] =
                red2[0][tid] + red2[1][tid] + red2[2][tid] + red2[3][tid];
    } else {
        float v2 = (mmin == 0.f) ? fmaxf(agg2, 0.f) : agg2; // masked max of agg2
        int cell = (coord[k * 4 + 1] * HH + coord[k * 4 + 2]) * WWID + coord[k * 4 + 3];
        int w = table[cell];                        // winner voxel for this cell
        atomicAdd(&compact[(size_t)w * 128 + lane], v1);
        atomicAdd(&compact[(size_t)w * 128 + 64 + lane], v2);
    }
}

// ---------------- layer-2 BN finalize: one block per channel ----------------
__global__ __launch_bounds__(256) void reduce2_kernel(
    const float* __restrict__ partial2, const float* __restrict__ g2,
    const float* __restrict__ be2, float* __restrict__ coef2)
{
    __shared__ float sred[4][2];
    int c = blockIdx.x;                 // 0..63
    int tid = threadIdx.x;
    float s = 0.f, q = 0.f;
    for (int r = tid; r < NBV; r += 256) {
        s += partial2[(size_t)r * 128 + c];
        q += partial2[(size_t)r * 128 + CM2 + c];
    }
#pragma unroll
    for (int off = 32; off > 0; off >>= 1) {
        s += __shfl_xor(s, off);
        q += __shfl_xor(q, off);
    }
    int wid = tid >> 6;
    if ((tid & 63) == 0) { sred[wid][0] = s; sred[wid][1] = q; }
    __syncthreads();
    if (tid == 0) {
        float S = sred[0][0] + sred[1][0] + sred[2][0] + sred[3][0];
        float Q = sred[0][1] + sred[1][1] + sred[2][1] + sred[3][1];
        float inv = 1.f / (float)NPTS;
        float mu = S * inv;
        float var = Q * inv - mu * mu;
        float a = g2[c] * rsqrtf(var + EPSBN);
        coef2[c] = a;
        coef2[CM2 + c] = be2[c] - mu * a;
    }
}

// ---------------- fused output pass: every 64B written exactly once ----------
// thread -> 4 consecutive float4 (64B, one cell fragment); occupied cells
// (1.07%) copy from compact[winner], rest write zeros. 721 MB streamed once.
#define NWT (NCELL * 32 / 4)   // 11,264,000 threads (4 float4 each)
#define NBW (NWT / 256)        // 44,000 blocks
__global__ __launch_bounds__(256) void write_kernel(
    vfloat4* __restrict__ out, const int* __restrict__ table,
    const float* __restrict__ compact)
{
    int t = blockIdx.x * 256 + threadIdx.x;   // < 11,264,000
    size_t f4 = (size_t)t * 4;
    int cell = (int)(f4 >> 5);                // 32 float4 per cell
    int w = table[cell];
    if (w < KVOX) {
        const vfloat4* src =
            reinterpret_cast<const vfloat4*>(&compact[(size_t)w * 128 + ((f4 & 31) << 2)]);
        out[f4 + 0] = src[0]; out[f4 + 1] = src[1];
        out[f4 + 2] = src[2]; out[f4 + 3] = src[3];
    } else {
        const vfloat4 z = {0.f, 0.f, 0.f, 0.f};
        out[f4 + 0] = z; out[f4 + 1] = z; out[f4 + 2] = z; out[f4 + 3] = z;
    }
}

extern "C" void kernel_launch(void* const* d_in, const int* in_sizes, int n_in,
                              void* d_out, int out_size, void* d_ws, size_t ws_size,
                              hipStream_t stream)
{
    const float* feat = (const float*)d_in[0];
    const int*   coord = (const int*)d_in[1];
    // d_in[2] = bs (==1, unused)
    const float* W1  = (const float*)d_in[3];
    const float* b1  = (const float*)d_in[4];
    const float* g1  = (const float*)d_in[5];
    const float* be1 = (const float*)d_in[6];
    const float* W2  = (const float*)d_in[7];
    const float* b2  = (const float*)d_in[8];
    const float* g2  = (const float*)d_in[9];
    const float* be2 = (const float*)d_in[10];
    float* out = (float*)d_out;

    // ws layout (all 16B aligned): table 5.632MB | compact 7.68MB |
    // partial1 32KB | partial2 1.92MB | coef1 | coef2   (~15.3 MB total)
    int*   table    = (int*)d_ws;
    float* compact  = (float*)d_ws + NCELL;
    float* partial1 = compact + KVOX * 128;
    float* partial2 = partial1 + NB1 * 32;
    float* coef1    = partial2 + NBV * 128;
    float* coef2    = coef1 + 32;

    init_kernel<<<NBI, 256, 0, stream>>>((vint4*)table, (vfloat4*)compact);
    stats1_kernel<<<NB1, 256, 0, stream>>>(feat, coord, W1, b1, partial1, table);
    reduce1_kernel<<<1, 256, 0, stream>>>(partial1, g1, be1, coef1);
    vfe_kernel<false><<<NBV, 256, 0, stream>>>(feat, W1, b1, coef1, W2, b2,
                                               nullptr, nullptr, nullptr,
                                               partial2, nullptr);
    reduce2_kernel<<<CM2, 256, 0, stream>>>(partial2, g2, be2, coef2);
    vfe_kernel<true><<<NBV, 256, 0, stream>>>(feat, W1, b1, coef1, W2, b2,
                                              coef2, coord, table,
                                              nullptr, compact);
    write_kernel<<<NBW, 256, 0, stream>>>((vfloat4*)out, table, compact);
}

// Round 9
// 836.361 us; speedup vs baseline: 1.2126x; 1.1188x over previous
//
#include <hip/hip_runtime.h>
#include <math.h>

#define KVOX 15000
#define TP 35
#define CIN 7
#define CM1 16
#define CM2 64
#define NPTS (KVOX * TP)
#define DD 10
#define HH 400
#define WWID 352
#define NCELL (DD * HH * WWID)   // 1,408,000
#define EPSBN 1e-5f
#define NB1 256
#define NBV 3750   // KVOX / 4 voxels-per-block

typedef float vfloat4 __attribute__((ext_vector_type(4)));
typedef int   vint4   __attribute__((ext_vector_type(4)));

// ---------------- init: table = INT_MAX (5.6 MB) ----------------
#define NT4 (NCELL / 4)              // 352,000 int4 -> 1375 blocks exact
__global__ __launch_bounds__(256) void init_kernel(vint4* __restrict__ table4)
{
    int i = blockIdx.x * 256 + threadIdx.x;
    table4[i] = (vint4){0x7FFFFFFF, 0x7FFFFFFF, 0x7FFFFFFF, 0x7FFFFFFF};
}

// ---------------- layer-1 BN stats + winner-table build ----------------
__global__ __launch_bounds__(256) void stats1_kernel(
    const float* __restrict__ feat, const int* __restrict__ coord,
    const float* __restrict__ W1, const float* __restrict__ b1,
    float* __restrict__ partial1, int* __restrict__ table)
{
    __shared__ float w1s[CIN * CM1];
    __shared__ float b1s[CM1];
    __shared__ float red[4][32];
    int tid = threadIdx.x;
    if (tid < CIN * CM1) w1s[tid] = W1[tid];
    if (tid < CM1) b1s[tid] = b1[tid];

    // cell -> winner(min voxel id); duplicate-coordinate voxels share winner
    int g = blockIdx.x * 256 + tid;
    if (g < KVOX) {
        int cell = (coord[g * 4 + 1] * HH + coord[g * 4 + 2]) * WWID + coord[g * 4 + 3];
        atomicMin(&table[cell], g);
    }
    __syncthreads();

    float s[CM1], q[CM1];
#pragma unroll
    for (int c = 0; c < CM1; ++c) { s[c] = 0.f; q[c] = 0.f; }

    for (int i = blockIdx.x * 256 + tid; i < NPTS; i += NB1 * 256) {
        float f[CIN];
#pragma unroll
        for (int j = 0; j < CIN; ++j) f[j] = feat[(size_t)i * CIN + j];
#pragma unroll
        for (int c = 0; c < CM1; ++c) {
            float acc = b1s[c];
#pragma unroll
            for (int j = 0; j < CIN; ++j) acc = fmaf(f[j], w1s[j * CM1 + c], acc);
            float pw = fmaxf(acc, 0.f);
            s[c] += pw; q[c] += pw * pw;
        }
    }
#pragma unroll
    for (int c = 0; c < CM1; ++c) {
#pragma unroll
        for (int off = 32; off > 0; off >>= 1) {
            s[c] += __shfl_xor(s[c], off);
            q[c] += __shfl_xor(q[c], off);
        }
    }
    int wid = tid >> 6, lane = tid & 63;
    if (lane == 0) {
#pragma unroll
        for (int c = 0; c < CM1; ++c) { red[wid][c] = s[c]; red[wid][CM1 + c] = q[c]; }
    }
    __syncthreads();
    if (tid < 32)
        partial1[blockIdx.x * 32 + tid] =
            red[0][tid] + red[1][tid] + red[2][tid] + red[3][tid];
}

__global__ __launch_bounds__(256) void reduce1_kernel(
    const float* __restrict__ partial1, const float* __restrict__ g1,
    const float* __restrict__ be1, float* __restrict__ coef1)
{
    __shared__ float acc[8][32];
    __shared__ float tot[32];
    int tid = threadIdx.x;
    int c = tid & 31, part = tid >> 5;
    float v = 0.f;
    for (int b = part; b < NB1; b += 8) v += partial1[b * 32 + c];
    acc[part][c] = v;
    __syncthreads();
    if (tid < 32) {
        float t = 0.f;
#pragma unroll
        for (int p = 0; p < 8; ++p) t += acc[p][tid];
        tot[tid] = t;
    }
    __syncthreads();
    if (tid < CM1) {
        float inv = 1.f / (float)NPTS;
        float mu = tot[tid] * inv;
        float var = tot[CM1 + tid] * inv - mu * mu;
        float a = g1[tid] * rsqrtf(var + EPSBN);
        coef1[tid] = a;                       // scale
        coef1[CM1 + tid] = be1[tid] - mu * a; // shift
    }
}

// ------------- SINGLE VFE pass: L1+L2, BN2 partials, pw2 extrema -------------
// BN is affine (bn = a*pw + d), so all voxelwise maxes reduce to per-channel
// extrema of pw2 — no second pass over the data needed.
__global__ __launch_bounds__(256) void vfe_once_kernel(
    const float* __restrict__ feat,
    const float* __restrict__ W1g, const float* __restrict__ b1g,
    const float* __restrict__ coef1,
    const float* __restrict__ W2g, const float* __restrict__ b2g,
    float* __restrict__ partial2,
    float* __restrict__ ext,        // [KVOX][4][64]: maxv,minv,maxa,mina
    int*   __restrict__ flags,      // [KVOX]: any masked-out row?
    vfloat4* __restrict__ compact4) // zeroed here for finalize's atomics
{
    __shared__ float sfeat[4][TP * CIN + 11];      // 245 -> 256 per wave
    alignas(16) __shared__ float scat[4][TP * 32]; // 1120 per wave
    __shared__ float smask[4][TP + 5];
    __shared__ float red2[4][2 * CM2];

    int tid = threadIdx.x, wid = tid >> 6, lane = tid & 63;
    int k = blockIdx.x * 4 + wid;                  // exact: NBV*4 == KVOX
    int tg = lane >> 4, c1 = lane & 15;

    float w1r[CIN];
#pragma unroll
    for (int j = 0; j < CIN; ++j) w1r[j] = W1g[j * CM1 + c1];
    float b1r = b1g[c1];
    float a1r = coef1[c1], d1r = coef1[CM1 + c1];
    float w2r[32];
#pragma unroll
    for (int j = 0; j < 32; ++j) w2r[j] = W2g[j * CM2 + lane];
    float b2r = b2g[lane];

    float* F = sfeat[wid];
    float* CT = scat[wid];
    float* M = smask[wid];

    for (int i = lane; i < TP * CIN; i += 64)
        F[i] = feat[(size_t)k * (TP * CIN) + i];
    __syncthreads();

    // ---- phase 1: pw1 -> bn1, unmasked max over T, masked cat ----
    float maxv = -INFINITY;
#pragma unroll
    for (int it = 0; it < 9; ++it) {
        int t = tg + 4 * it;
        if (t < TP) {
            float fv0 = F[t * CIN];
            float m7 = fv0;
            float acc = fmaf(fv0, w1r[0], b1r);
#pragma unroll
            for (int j = 1; j < CIN; ++j) {
                float fv = F[t * CIN + j];
                m7 = fmaxf(m7, fv);
                acc = fmaf(fv, w1r[j], acc);
            }
            float maskv = (m7 != 0.f) ? 1.f : 0.f;
            float pw = fmaxf(acc, 0.f);
            float bn = fmaf(pw, a1r, d1r);
            maxv = fmaxf(maxv, bn);               // agg1 uses UNMASKED bn
            CT[t * 32 + c1] = bn * maskv;
            if (c1 == 0) M[t] = maskv;
        }
    }
    maxv = fmaxf(maxv, __shfl_xor(maxv, 16));
    maxv = fmaxf(maxv, __shfl_xor(maxv, 32));
#pragma unroll
    for (int it = 0; it < 9; ++it) {
        int t = tg + 4 * it;
        if (t < TP) CT[t * 32 + 16 + c1] = maxv * M[t];
    }
    // within-wave LDS deps only (in-order LDS) — no block barrier needed

    // ---- phase 2: lane = L2 output channel; stats + extrema in one sweep ----
    float s_acc = 0.f, q_acc = 0.f;
    float pwmax_v = -INFINITY, pwmin_v = INFINITY;
    float pwmax_a = -INFINITY, pwmin_a = INFINITY;
    float mmin = 1.f;
    for (int t = 0; t < TP; ++t) {
        const float4* r4 = reinterpret_cast<const float4*>(&CT[t * 32]);
        float acc0 = b2r, acc1 = 0.f;
#pragma unroll
        for (int i = 0; i < 8; i += 2) {
            float4 va = r4[i], vb = r4[i + 1];
            acc0 = fmaf(va.x, w2r[4 * i + 0], acc0);
            acc0 = fmaf(va.y, w2r[4 * i + 1], acc0);
            acc0 = fmaf(va.z, w2r[4 * i + 2], acc0);
            acc0 = fmaf(va.w, w2r[4 * i + 3], acc0);
            acc1 = fmaf(vb.x, w2r[4 * i + 4], acc1);
            acc1 = fmaf(vb.y, w2r[4 * i + 5], acc1);
            acc1 = fmaf(vb.z, w2r[4 * i + 6], acc1);
            acc1 = fmaf(vb.w, w2r[4 * i + 7], acc1);
        }
        float pw = fmaxf(acc0 + acc1, 0.f);
        s_acc += pw; q_acc += pw * pw;
        float mk = M[t];
        mmin = fminf(mmin, mk);
        pwmax_a = fmaxf(pwmax_a, pw);
        pwmin_a = fminf(pwmin_a, pw);
        pwmax_v = fmaxf(pwmax_v, (mk != 0.f) ? pw : -INFINITY);
        pwmin_v = fminf(pwmin_v, (mk != 0.f) ? pw : INFINITY);
    }

    // extrema + flag (coalesced 1 KB per wave)
    float* E = ext + (size_t)k * 256;
    E[lane] = pwmax_v; E[64 + lane] = pwmin_v;
    E[128 + lane] = pwmax_a; E[192 + lane] = pwmin_a;
    if (lane == 0) flags[k] = (mmin == 0.f) ? 1 : 0;

    // BN2 partial sums
    red2[wid][lane] = s_acc;
    red2[wid][CM2 + lane] = q_acc;
    __syncthreads();
    if (tid < 2 * CM2)
        partial2[(size_t)blockIdx.x * (2 * CM2) + tid] =
            red2[0][tid] + red2[1][tid] + red2[2][tid] + red2[3][tid];

    // zero this block's compact slice (4 voxels x 512 B) for finalize
    if (tid < 128)
        compact4[(size_t)blockIdx.x * 128 + tid] = (vfloat4){0.f, 0.f, 0.f, 0.f};
}

// ---------------- layer-2 BN finalize: one block per channel ----------------
__global__ __launch_bounds__(256) void reduce2_kernel(
    const float* __restrict__ partial2, const float* __restrict__ g2,
    const float* __restrict__ be2, float* __restrict__ coef2)
{
    __shared__ float sred[4][2];
    int c = blockIdx.x;                 // 0..63
    int tid = threadIdx.x;
    float s = 0.f, q = 0.f;
    for (int r = tid; r < NBV; r += 256) {
        s += partial2[(size_t)r * 128 + c];
        q += partial2[(size_t)r * 128 + CM2 + c];
    }
#pragma unroll
    for (int off = 32; off > 0; off >>= 1) {
        s += __shfl_xor(s, off);
        q += __shfl_xor(q, off);
    }
    int wid = tid >> 6;
    if ((tid & 63) == 0) { sred[wid][0] = s; sred[wid][1] = q; }
    __syncthreads();
    if (tid == 0) {
        float S = sred[0][0] + sred[1][0] + sred[2][0] + sred[3][0];
        float Q = sred[0][1] + sred[1][1] + sred[2][1] + sred[3][1];
        float inv = 1.f / (float)NPTS;
        float mu = S * inv;
        float var = Q * inv - mu * mu;
        float a = g2[c] * rsqrtf(var + EPSBN);
        coef2[c] = a;
        coef2[CM2 + c] = be2[c] - mu * a;
    }
}

// ---- finalize: bn2 on extrema -> v1/v2, accumulate into compact[winner] ----
__global__ __launch_bounds__(256) void finalize_kernel(
    const float* __restrict__ ext, const int* __restrict__ flags,
    const int* __restrict__ coord, const float* __restrict__ coef2,
    const int* __restrict__ table, float* __restrict__ compact)
{
    int tid = threadIdx.x;
    int k = blockIdx.x * 2 + (tid >> 7);      // 7500 blocks x 2 voxels
    int sub = tid & 127;
    int c = sub & 63, half = sub >> 6;
    float a = coef2[c], d = coef2[CM2 + c];
    const float* E = ext + (size_t)k * 256 + half * 128;
    float hi = E[c], lo = E[64 + c];
    // max_t(a*pw+d) = a>=0 ? a*max+d : a*min+d
    float val = (a >= 0.f) ? fmaf(a, hi, d) : fmaf(a, lo, d);
    if (flags[k]) val = fmaxf(val, 0.f);      // masked rows contribute 0
    int cell = (coord[k * 4 + 1] * HH + coord[k * 4 + 2]) * WWID + coord[k * 4 + 3];
    int w = table[cell];
    atomicAdd(&compact[(size_t)w * 128 + sub], val);
}

// -------- fused output: lane-contiguous float4, 721 MB written once --------
#define NBW (NCELL * 32 / 256)   // 176,000 blocks
__global__ __launch_bounds__(256) void write_kernel(
    vfloat4* __restrict__ out, const int* __restrict__ table,
    const vfloat4* __restrict__ compact4)
{
    int i = blockIdx.x * 256 + threadIdx.x;   // float4 index < 45,056,000
    int cell = i >> 5;                        // 32 float4 per cell
    int w = table[cell];
    vfloat4 v = {0.f, 0.f, 0.f, 0.f};
    if (w < KVOX) v = compact4[w * 32 + (i & 31)];
    out[i] = v;
}

extern "C" void kernel_launch(void* const* d_in, const int* in_sizes, int n_in,
                              void* d_out, int out_size, void* d_ws, size_t ws_size,
                              hipStream_t stream)
{
    const float* feat = (const float*)d_in[0];
    const int*   coord = (const int*)d_in[1];
    // d_in[2] = bs (==1, unused)
    const float* W1  = (const float*)d_in[3];
    const float* b1  = (const float*)d_in[4];
    const float* g1  = (const float*)d_in[5];
    const float* be1 = (const float*)d_in[6];
    const float* W2  = (const float*)d_in[7];
    const float* b2  = (const float*)d_in[8];
    const float* g2  = (const float*)d_in[9];
    const float* be2 = (const float*)d_in[10];
    float* out = (float*)d_out;

    // ws layout (16B-aligned segments), ~30.7 MB total:
    int*   table    = (int*)d_ws;                    // 5.632 MB
    float* compact  = (float*)d_ws + NCELL;          // 7.68 MB
    float* ext      = compact + (size_t)KVOX * 128;  // 15.36 MB
    float* partial1 = ext + (size_t)KVOX * 256;      // 32 KB
    float* partial2 = partial1 + NB1 * 32;           // 1.92 MB
    int*   flags    = (int*)(partial2 + NBV * 128);  // 60 KB
    float* coef1    = (float*)(flags + KVOX);
    float* coef2    = coef1 + 32;

    init_kernel<<<NT4 / 256, 256, 0, stream>>>((vint4*)table);
    stats1_kernel<<<NB1, 256, 0, stream>>>(feat, coord, W1, b1, partial1, table);
    reduce1_kernel<<<1, 256, 0, stream>>>(partial1, g1, be1, coef1);
    vfe_once_kernel<<<NBV, 256, 0, stream>>>(feat, W1, b1, coef1, W2, b2,
                                             partial2, ext, flags,
                                             (vfloat4*)compact);
    reduce2_kernel<<<CM2, 256, 0, stream>>>(partial2, g2, be2, coef2);
    finalize_kernel<<<KVOX / 2, 256, 0, stream>>>(ext, flags, coord, coef2,
                                                  table, compact);
    write_kernel<<<NBW, 256, 0, stream>>>((vfloat4*)out, table, (vfloat4*)compact);
}

// Round 10
// 788.965 us; speedup vs baseline: 1.2854x; 1.0601x over previous
//
#include <hip/hip_runtime.h>
#include <math.h>

#define KVOX 15000
#define TP 35
#define CIN 7
#define CM1 16
#define CM2 64
#define NPTS (KVOX * TP)
#define DD 10
#define HH 400
#define WWID 352
#define NCELL (DD * HH * WWID)   // 1,408,000
#define EPSBN 1e-5f
#define NB1 256
#define NBV 3750   // KVOX / 4 voxels-per-block
#define NBW 2048   // write-kernel blocks (grid-stride)

typedef float vfloat4 __attribute__((ext_vector_type(4)));
typedef int   vint4   __attribute__((ext_vector_type(4)));
typedef short bf16x8  __attribute__((ext_vector_type(8)));
typedef float f32x4   __attribute__((ext_vector_type(4)));

// RNE float->bf16 bits (finite inputs)
__device__ inline unsigned short f2b(float x)
{
    unsigned int u = __float_as_uint(x);
    unsigned int r = (u + 0x7FFFu + ((u >> 16) & 1u)) >> 16;
    return (unsigned short)r;
}

// ---------------- init: table = INT_MAX (5.6 MB) ----------------
#define NT4 (NCELL / 4)              // 352,000 int4 -> 1375 blocks exact
__global__ __launch_bounds__(256) void init_kernel(vint4* __restrict__ table4)
{
    int i = blockIdx.x * 256 + threadIdx.x;
    table4[i] = (vint4){0x7FFFFFFF, 0x7FFFFFFF, 0x7FFFFFFF, 0x7FFFFFFF};
}

// ---------------- layer-1 BN stats + winner-table build ----------------
__global__ __launch_bounds__(256) void stats1_kernel(
    const float* __restrict__ feat, const int* __restrict__ coord,
    const float* __restrict__ W1, const float* __restrict__ b1,
    float* __restrict__ partial1, int* __restrict__ table)
{
    __shared__ float w1s[CIN * CM1];
    __shared__ float b1s[CM1];
    __shared__ float red[4][32];
    int tid = threadIdx.x;
    if (tid < CIN * CM1) w1s[tid] = W1[tid];
    if (tid < CM1) b1s[tid] = b1[tid];

    int g = blockIdx.x * 256 + tid;
    if (g < KVOX) {
        int cell = (coord[g * 4 + 1] * HH + coord[g * 4 + 2]) * WWID + coord[g * 4 + 3];
        atomicMin(&table[cell], g);
    }
    __syncthreads();

    float s[CM1], q[CM1];
#pragma unroll
    for (int c = 0; c < CM1; ++c) { s[c] = 0.f; q[c] = 0.f; }

    for (int i = blockIdx.x * 256 + tid; i < NPTS; i += NB1 * 256) {
        float f[CIN];
#pragma unroll
        for (int j = 0; j < CIN; ++j) f[j] = feat[(size_t)i * CIN + j];
#pragma unroll
        for (int c = 0; c < CM1; ++c) {
            float acc = b1s[c];
#pragma unroll
            for (int j = 0; j < CIN; ++j) acc = fmaf(f[j], w1s[j * CM1 + c], acc);
            float pw = fmaxf(acc, 0.f);
            s[c] += pw; q[c] += pw * pw;
        }
    }
#pragma unroll
    for (int c = 0; c < CM1; ++c) {
#pragma unroll
        for (int off = 32; off > 0; off >>= 1) {
            s[c] += __shfl_xor(s[c], off);
            q[c] += __shfl_xor(q[c], off);
        }
    }
    int wid = tid >> 6, lane = tid & 63;
    if (lane == 0) {
#pragma unroll
        for (int c = 0; c < CM1; ++c) { red[wid][c] = s[c]; red[wid][CM1 + c] = q[c]; }
    }
    __syncthreads();
    if (tid < 32)
        partial1[blockIdx.x * 32 + tid] =
            red[0][tid] + red[1][tid] + red[2][tid] + red[3][tid];
}

__global__ __launch_bounds__(256) void reduce1_kernel(
    const float* __restrict__ partial1, const float* __restrict__ g1,
    const float* __restrict__ be1, float* __restrict__ coef1)
{
    __shared__ float acc[8][32];
    __shared__ float tot[32];
    int tid = threadIdx.x;
    int c = tid & 31, part = tid >> 5;
    float v = 0.f;
    for (int b = part; b < NB1; b += 8) v += partial1[b * 32 + c];
    acc[part][c] = v;
    __syncthreads();
    if (tid < 32) {
        float t = 0.f;
#pragma unroll
        for (int p = 0; p < 8; ++p) t += acc[p][tid];
        tot[tid] = t;
    }
    __syncthreads();
    if (tid < CM1) {
        float inv = 1.f / (float)NPTS;
        float mu = tot[tid] * inv;
        float var = tot[CM1 + tid] * inv - mu * mu;
        float a = g1[tid] * rsqrtf(var + EPSBN);
        coef1[tid] = a;
        coef1[CM1 + tid] = be1[tid] - mu * a;
    }
}

// ------------- SINGLE VFE pass, phase-2 via MFMA (bf16 inputs) -------------
// Per wave (=voxel): cat1 [48x32] bf16 in LDS (rows 35-47 zero), W2 bf16
// B-frags in VGPRs. 3 ds_read_b128 A-loads + 12 mfma_f32_16x16x32_bf16
// replace 280 broadcast ds_read_b128 + 1120 scalar FMAs.
__global__ __launch_bounds__(256) void vfe_once_kernel(
    const float* __restrict__ feat,
    const float* __restrict__ W1g, const float* __restrict__ b1g,
    const float* __restrict__ coef1,
    const float* __restrict__ W2g, const float* __restrict__ b2g,
    float* __restrict__ partial2,
    float* __restrict__ ext,        // [KVOX][4][64]: maxv,minv,maxa,mina
    int*   __restrict__ flags,      // [KVOX]: any masked-out row?
    vfloat4* __restrict__ compact4) // zeroed here for finalize's atomics
{
    __shared__ float sfeat[4][256];
    __shared__ vint4 sct4[4][288];   // 48 rows x 96 B bf16 tile per wave
    __shared__ float smask[4][48];
    __shared__ float red2[4][2 * CM2];

    int tid = threadIdx.x, wid = tid >> 6, lane = tid & 63;
    int k = blockIdx.x * 4 + wid;                  // exact: NBV*4 == KVOX
    int tg = lane >> 4, c1 = lane & 15;

    // layer-1 per-lane constants
    float w1r[CIN];
#pragma unroll
    for (int j = 0; j < CIN; ++j) w1r[j] = W1g[j * CM1 + c1];
    float b1r = b1g[c1];
    float a1r = coef1[c1], d1r = coef1[CM1 + c1];

    // W2 B-fragments (bf16) + bias. B[k][n]: n = 16*nt + (lane&15),
    // k = (lane>>4)*8 + j.  W2 row-major [32][64], L2-hot across blocks.
    bf16x8 bfr[4];
    float bias[4];
#pragma unroll
    for (int nt = 0; nt < 4; ++nt) {
        bias[nt] = b2g[nt * 16 + c1];
#pragma unroll
        for (int j = 0; j < 8; ++j)
            bfr[nt][j] = (short)f2b(W2g[(tg * 8 + j) * 64 + nt * 16 + c1]);
    }

    float* F = sfeat[wid];
    unsigned short* CT = (unsigned short*)sct4[wid];
    float* M = smask[wid];

    // stage feature tile; zero pad rows 35..47 of CT (1248 B) + M tail
    for (int i = lane; i < TP * CIN; i += 64)
        F[i] = feat[(size_t)k * (TP * CIN) + i];
    {
        vint4 z = {0, 0, 0, 0};
        vint4* pz = (vint4*)(CT + 35 * 48);   // byte 3360, 16B-aligned
        pz[lane] = z;
        if (lane < 14) pz[64 + lane] = z;
        if (lane < 13) M[35 + lane] = 0.f;
    }
    // within-wave LDS deps only (in-order LDS)

    // ---- phase 1: pw1 -> bn1, unmasked max over T, masked cat (bf16) ----
    float maxv = -INFINITY;
#pragma unroll
    for (int it = 0; it < 9; ++it) {
        int t = tg + 4 * it;
        if (t < TP) {
            float fv0 = F[t * CIN];
            float m7 = fv0;
            float acc = fmaf(fv0, w1r[0], b1r);
#pragma unroll
            for (int j = 1; j < CIN; ++j) {
                float fv = F[t * CIN + j];
                m7 = fmaxf(m7, fv);
                acc = fmaf(fv, w1r[j], acc);
            }
            float maskv = (m7 != 0.f) ? 1.f : 0.f;
            float pw = fmaxf(acc, 0.f);
            float bn = fmaf(pw, a1r, d1r);
            maxv = fmaxf(maxv, bn);               // agg1 uses UNMASKED bn
            CT[t * 48 + c1] = f2b(bn * maskv);
            if (c1 == 0) M[t] = maskv;
        }
    }
    maxv = fmaxf(maxv, __shfl_xor(maxv, 16));
    maxv = fmaxf(maxv, __shfl_xor(maxv, 32));
#pragma unroll
    for (int it = 0; it < 9; ++it) {
        int t = tg + 4 * it;
        if (t < TP) CT[t * 48 + 16 + c1] = f2b(maxv * M[t]);
    }

    // ---- phase 2: 12 MFMAs. A[m][k]: m = lane&15 (+16*mt), k = tg*8+j ----
    f32x4 acc[3][4] = {};
#pragma unroll
    for (int mt = 0; mt < 3; ++mt) {
        bf16x8 a = ((bf16x8*)sct4[wid])[(16 * mt + c1) * 6 + tg];
#pragma unroll
        for (int nt = 0; nt < 4; ++nt)
            acc[mt][nt] = __builtin_amdgcn_mfma_f32_16x16x32_bf16(
                a, bfr[nt], acc[mt][nt], 0, 0, 0);
    }

    // ---- epilogue: bias+relu, stats + extrema; C row=(lane>>4)*4+reg ----
    float s[4] = {0.f, 0.f, 0.f, 0.f}, q[4] = {0.f, 0.f, 0.f, 0.f};
    float mxv[4], mnv[4], mxa[4], mna[4];
#pragma unroll
    for (int nt = 0; nt < 4; ++nt) {
        mxv[nt] = -INFINITY; mnv[nt] = INFINITY;
        mxa[nt] = -INFINITY; mna[nt] = INFINITY;
    }
    float mmin = 1.f;
#pragma unroll
    for (int mt = 0; mt < 3; ++mt) {
#pragma unroll
        for (int r = 0; r < 4; ++r) {
            int row = 16 * mt + tg * 4 + r;
            bool live = row < TP;
            float mk = M[row];
            if (live) mmin = fminf(mmin, mk);
            bool vld = live && (mk != 0.f);
#pragma unroll
            for (int nt = 0; nt < 4; ++nt) {
                float pw = fmaxf(acc[mt][nt][r] + bias[nt], 0.f);
                if (live) {
                    s[nt] += pw; q[nt] += pw * pw;
                    mxa[nt] = fmaxf(mxa[nt], pw);
                    mna[nt] = fminf(mna[nt], pw);
                }
                if (vld) {
                    mxv[nt] = fmaxf(mxv[nt], pw);
                    mnv[nt] = fminf(mnv[nt], pw);
                }
            }
        }
    }
    // reduce over the 4 lane-groups (rows partitioned by lane>>4)
#pragma unroll
    for (int nt = 0; nt < 4; ++nt) {
        s[nt] += __shfl_xor(s[nt], 16);  s[nt] += __shfl_xor(s[nt], 32);
        q[nt] += __shfl_xor(q[nt], 16);  q[nt] += __shfl_xor(q[nt], 32);
        mxv[nt] = fmaxf(mxv[nt], __shfl_xor(mxv[nt], 16));
        mxv[nt] = fmaxf(mxv[nt], __shfl_xor(mxv[nt], 32));
        mnv[nt] = fminf(mnv[nt], __shfl_xor(mnv[nt], 16));
        mnv[nt] = fminf(mnv[nt], __shfl_xor(mnv[nt], 32));
        mxa[nt] = fmaxf(mxa[nt], __shfl_xor(mxa[nt], 16));
        mxa[nt] = fmaxf(mxa[nt], __shfl_xor(mxa[nt], 32));
        mna[nt] = fminf(mna[nt], __shfl_xor(mna[nt], 16));
        mna[nt] = fminf(mna[nt], __shfl_xor(mna[nt], 32));
    }
    mmin = fminf(mmin, __shfl_xor(mmin, 16));
    mmin = fminf(mmin, __shfl_xor(mmin, 32));

    // lane owns channel=lane -> select nt = lane>>4 (static ternary chain)
    float o_mxv = tg == 0 ? mxv[0] : tg == 1 ? mxv[1] : tg == 2 ? mxv[2] : mxv[3];
    float o_mnv = tg == 0 ? mnv[0] : tg == 1 ? mnv[1] : tg == 2 ? mnv[2] : mnv[3];
    float o_mxa = tg == 0 ? mxa[0] : tg == 1 ? mxa[1] : tg == 2 ? mxa[2] : mxa[3];
    float o_mna = tg == 0 ? mna[0] : tg == 1 ? mna[1] : tg == 2 ? mna[2] : mna[3];
    float o_s   = tg == 0 ? s[0]   : tg == 1 ? s[1]   : tg == 2 ? s[2]   : s[3];
    float o_q   = tg == 0 ? q[0]   : tg == 1 ? q[1]   : tg == 2 ? q[2]   : q[3];

    float* E = ext + (size_t)k * 256;
    E[lane] = o_mxv; E[64 + lane] = o_mnv;
    E[128 + lane] = o_mxa; E[192 + lane] = o_mna;
    if (lane == 0) flags[k] = (mmin == 0.f) ? 1 : 0;

    red2[wid][lane] = o_s;
    red2[wid][CM2 + lane] = o_q;
    __syncthreads();
    if (tid < 2 * CM2)
        partial2[(size_t)blockIdx.x * (2 * CM2) + tid] =
            red2[0][tid] + red2[1][tid] + red2[2][tid] + red2[3][tid];

    // zero this block's compact slice (4 voxels x 512 B) for finalize
    if (tid < 128)
        compact4[(size_t)blockIdx.x * 128 + tid] = (vfloat4){0.f, 0.f, 0.f, 0.f};
}

// ---------------- layer-2 BN finalize: one block per channel ----------------
__global__ __launch_bounds__(256) void reduce2_kernel(
    const float* __restrict__ partial2, const float* __restrict__ g2,
    const float* __restrict__ be2, float* __restrict__ coef2)
{
    __shared__ float sred[4][2];
    int c = blockIdx.x;                 // 0..63
    int tid = threadIdx.x;
    float s = 0.f, q = 0.f;
    for (int r = tid; r < NBV; r += 256) {
        s += partial2[(size_t)r * 128 + c];
        q += partial2[(size_t)r * 128 + CM2 + c];
    }
#pragma unroll
    for (int off = 32; off > 0; off >>= 1) {
        s += __shfl_xor(s, off);
        q += __shfl_xor(q, off);
    }
    int wid = tid >> 6;
    if ((tid & 63) == 0) { sred[wid][0] = s; sred[wid][1] = q; }
    __syncthreads();
    if (tid == 0) {
        float S = sred[0][0] + sred[1][0] + sred[2][0] + sred[3][0];
        float Q = sred[0][1] + sred[1][1] + sred[2][1] + sred[3][1];
        float inv = 1.f / (float)NPTS;
        float mu = S * inv;
        float var = Q * inv - mu * mu;
        float a = g2[c] * rsqrtf(var + EPSBN);
        coef2[c] = a;
        coef2[CM2 + c] = be2[c] - mu * a;
    }
}

// ---- finalize: bn2 on extrema -> v1/v2, accumulate into compact[winner] ----
__global__ __launch_bounds__(256) void finalize_kernel(
    const float* __restrict__ ext, const int* __restrict__ flags,
    const int* __restrict__ coord, const float* __restrict__ coef2,
    const int* __restrict__ table, float* __restrict__ compact)
{
    int tid = threadIdx.x;
    int k = blockIdx.x * 2 + (tid >> 7);      // 7500 blocks x 2 voxels
    int sub = tid & 127;
    int c = sub & 63, half = sub >> 6;
    float a = coef2[c], d = coef2[CM2 + c];
    const float* E = ext + (size_t)k * 256 + half * 128;
    float hi = E[c], lo = E[64 + c];
    float val = (a >= 0.f) ? fmaf(a, hi, d) : fmaf(a, lo, d);
    if (flags[k]) val = fmaxf(val, 0.f);
    int cell = (coord[k * 4 + 1] * HH + coord[k * 4 + 2]) * WWID + coord[k * 4 + 3];
    int w = table[cell];
    atomicAdd(&compact[(size_t)w * 128 + sub], val);
}

// -------- fused output: grid-stride float4, 721 MB written once --------
__global__ __launch_bounds__(256) void write_kernel(
    vfloat4* __restrict__ out, const int* __restrict__ table,
    const vfloat4* __restrict__ compact4)
{
    const int total = NCELL * 32;             // 45,056,000 float4
    int stride = NBW * 256;
    for (int i = blockIdx.x * 256 + threadIdx.x; i < total; i += stride) {
        int cell = i >> 5;                    // 32 float4 per cell
        int w = table[cell];
        vfloat4 v = {0.f, 0.f, 0.f, 0.f};
        if (w < KVOX) v = compact4[w * 32 + (i & 31)];
        out[i] = v;
    }
}

extern "C" void kernel_launch(void* const* d_in, const int* in_sizes, int n_in,
                              void* d_out, int out_size, void* d_ws, size_t ws_size,
                              hipStream_t stream)
{
    const float* feat = (const float*)d_in[0];
    const int*   coord = (const int*)d_in[1];
    // d_in[2] = bs (==1, unused)
    const float* W1  = (const float*)d_in[3];
    const float* b1  = (const float*)d_in[4];
    const float* g1  = (const float*)d_in[5];
    const float* be1 = (const float*)d_in[6];
    const float* W2  = (const float*)d_in[7];
    const float* b2  = (const float*)d_in[8];
    const float* g2  = (const float*)d_in[9];
    const float* be2 = (const float*)d_in[10];
    float* out = (float*)d_out;

    // ws layout (16B-aligned segments), ~30.7 MB total:
    int*   table    = (int*)d_ws;                    // 5.632 MB
    float* compact  = (float*)d_ws + NCELL;          // 7.68 MB
    float* ext      = compact + (size_t)KVOX * 128;  // 15.36 MB
    float* partial1 = ext + (size_t)KVOX * 256;      // 32 KB
    float* partial2 = partial1 + NB1 * 32;           // 1.92 MB
    int*   flags    = (int*)(partial2 + NBV * 128);  // 60 KB
    float* coef1    = (float*)(flags + KVOX);
    float* coef2    = coef1 + 32;

    init_kernel<<<NT4 / 256, 256, 0, stream>>>((vint4*)table);
    stats1_kernel<<<NB1, 256, 0, stream>>>(feat, coord, W1, b1, partial1, table);
    reduce1_kernel<<<1, 256, 0, stream>>>(partial1, g1, be1, coef1);
    vfe_once_kernel<<<NBV, 256, 0, stream>>>(feat, W1, b1, coef1, W2, b2,
                                             partial2, ext, flags,
                                             (vfloat4*)compact);
    reduce2_kernel<<<CM2, 256, 0, stream>>>(partial2, g2, be2, coef2);
    finalize_kernel<<<KVOX / 2, 256, 0, stream>>>(ext, flags, coord, coef2,
                                                  table, compact);
    write_kernel<<<NBW, 256, 0, stream>>>((vfloat4*)out, table, (vfloat4*)compact);
}